// Round 5
// baseline (63.303 us; speedup 1.0000x reference)
//
#include <hip/hip_runtime.h>

// ============================================================================
// PGALoss, analytically reduced:
//   per-point loss = sqrt(1 + d^2) + d,  d = NN distance
//   out = 0.5 * sum_dir clip((mean loss - 1)/2, 0, 1)
// d^2 = min_m(||p||^2 - 2 q.p) + ||q||^2
//
// R5: SGPR-broadcast brute force. Points are wave-uniform -> pair-transposed
// global layout {x0,x1,y0,y1,z0,z1,w0,w1} so uniform loads become s_load and
// each packed FMA reads one SGPR pair. 3 pk_fma + 1 min3 per (2 points x
// query) = 2.0 VALU/pair-eval. NO LDS, no syncthreads, no atomicMin.
// Deterministic partial buffer (plain stores), PS=128 -> 32 waves/CU.
// ============================================================================

typedef float v2f __attribute__((ext_vector_type(2)));

#define TPB 256
#define Q   8     // queries per thread; QPB = 2048

// ws layout:
//   [0,16)    : double acc[2]
//   [32,36)   : uint counter
//   [64, +512K)       : float4 P4[4N]   {x,y,z,||.||^2} (src b0,b1, tgt b0,b1)
//   [+512K, +1M)      : float pairBuf[2N pairs * 8]
//   [+1M, ...)        : float partial[PS][4N]

__global__ __launch_bounds__(256)
void prep_kernel(const float* __restrict__ src, const float* __restrict__ tgt,
                 float4* __restrict__ P4, float* __restrict__ pairBuf,
                 double* __restrict__ acc, unsigned int* __restrict__ counter,
                 int twoN) {                        // twoN = 2N points per input
    const int pi = blockIdx.x * 256 + threadIdx.x;  // pair index [0, twoN)
    if (pi < 2) acc[pi] = 0.0;
    if (pi == 2) *counter = 0u;
    if (pi >= twoN) return;
    float v[8];
    #pragma unroll
    for (int e = 0; e < 2; ++e) {
        const int g = 2 * pi + e;                   // flat point id [0, 2*twoN)
        const int which = g >= twoN ? 1 : 0;
        const int i = g - which * twoN;
        const float* in = which ? tgt : src;
        float x = in[3 * i], y = in[3 * i + 1], z = in[3 * i + 2];
        float w = x * x + y * y + z * z;
        P4[g] = make_float4(x, y, z, w);
        v[0 + e] = x; v[2 + e] = y; v[4 + e] = z; v[6 + e] = w;
    }
    float4* pb = (float4*)(pairBuf + (size_t)pi * 8);
    pb[0] = make_float4(v[0], v[1], v[2], v[3]);    // x0,x1,y0,y1
    pb[1] = make_float4(v[4], v[5], v[6], v[7]);    // z0,z1,w0,w1
}

__global__ __launch_bounds__(TPB)
void nn_kernel(const float4* __restrict__ P4, const float* __restrict__ pairBuf,
               float* __restrict__ partial, int N, int PS) {
    const int t    = threadIdx.x;
    const int QPB  = TPB * Q;            // 2048
    const int nqc  = N / QPB;            // 4
    const int bpt  = nqc * PS;
    const int task = blockIdx.x / bpt;   // dir = task>>1, batch = task&1
    const int rem  = blockIdx.x % bpt;
    const int qc   = rem / PS;
    const int pc   = rem % PS;
    const int ppb  = N / PS;             // points per block
    const int npairs = ppb / 2;

    // query cloud base == task*N in P4's flat order (src b0,b1, tgt b0,b1)
    const float4* qArr = P4 + (size_t)task * N + qc * QPB;
    // point cloud = same batch, other input -> flip dir bit
    const int ptask = task ^ 2;
    const float* pb = pairBuf + ((size_t)ptask * (N / 2) + (size_t)pc * npairs) * 8;

    v2f qx[Q], qy[Q], qz[Q];
    float best[Q];
    #pragma unroll
    for (int k = 0; k < Q; ++k) {
        float4 q = qArr[t + k * TPB];
        qx[k] = (v2f){-2.0f * q.x, -2.0f * q.x};
        qy[k] = (v2f){-2.0f * q.y, -2.0f * q.y};
        qz[k] = (v2f){-2.0f * q.z, -2.0f * q.z};
        best[k] = 3.4e38f;
    }

    #pragma unroll 8
    for (int j = 0; j < npairs; ++j) {
        const v2f* pp = (const v2f*)(pb + (size_t)j * 8);  // uniform -> s_load
        v2f px = pp[0], py = pp[1], pz = pp[2], pw = pp[3];
        #pragma unroll
        for (int k = 0; k < Q; ++k) {
            v2f d = __builtin_elementwise_fma(px, qx[k],
                    __builtin_elementwise_fma(py, qy[k],
                    __builtin_elementwise_fma(pz, qz[k], pw)));
            best[k] = fminf(fminf(d.x, d.y), best[k]);     // v_min3_f32
        }
    }

    // partial stores WITHOUT +qq (added in reduce); can be negative, fine.
    float* dst = partial + (size_t)pc * (4 * N) + (size_t)task * N + qc * QPB + t;
    #pragma unroll
    for (int k = 0; k < Q; ++k) dst[k * TPB] = best[k];
}

__global__ __launch_bounds__(256)
void reduce_kernel(const float4* __restrict__ P4, const float* __restrict__ partial,
                   double* __restrict__ acc, unsigned int* __restrict__ counter,
                   float* __restrict__ out, int N, int PS) {
    const int gq = blockIdx.x * 256 + threadIdx.x;   // [0, 4N), == P4 index
    const int QT = 4 * N;
    float best = 3.4e38f;
    for (int ps = 0; ps < PS; ++ps)
        best = fminf(best, partial[(size_t)ps * QT + gq]);
    float d2 = fmaxf(best + P4[gq].w, 0.0f);
    float f  = sqrtf(1.0f + d2) + sqrtf(d2);
    for (int o = 32; o > 0; o >>= 1) f += __shfl_down(f, o);
    const int dir = gq / (2 * N);                    // wave-uniform
    if ((threadIdx.x & 63) == 0) atomicAdd(&acc[dir], (double)f);
    __syncthreads();
    if (threadIdx.x == 0) {
        __threadfence();
        unsigned int old = atomicAdd(counter, 1u);
        if (old == gridDim.x - 1) {                  // last block finalizes
            double s0 = atomicAdd(&acc[0], 0.0);
            double s1 = atomicAdd(&acc[1], 0.0);
            double inv = 1.0 / (double)(2 * N);
            double l0 = (s0 * inv - 1.0) * 0.5;
            double l1 = (s1 * inv - 1.0) * 0.5;
            l0 = l0 < 0.0 ? 0.0 : (l0 > 1.0 ? 1.0 : l0);
            l1 = l1 < 0.0 ? 0.0 : (l1 > 1.0 ? 1.0 : l1);
            out[0] = (float)(0.5 * (l0 + l1));
        }
    }
}

extern "C" void kernel_launch(void* const* d_in, const int* in_sizes, int n_in,
                              void* d_out, int out_size, void* d_ws, size_t ws_size,
                              hipStream_t stream) {
    const float* src = (const float*)d_in[0];
    const float* tgt = (const float*)d_in[1];
    float* out = (float*)d_out;

    const int twoN = in_sizes[0] / 3;    // 16384 points per input
    const int N    = twoN / 2;           // 8192
    const int QT   = 4 * N;              // 32768 total queries

    double* acc           = (double*)d_ws;
    unsigned int* counter = (unsigned int*)((char*)d_ws + 32);
    float4* P4            = (float4*)((char*)d_ws + 64);
    float* pairBuf        = (float*)((char*)d_ws + 64 + (size_t)2 * twoN * 16);
    size_t fixed          = 64 + (size_t)2 * twoN * 16 + (size_t)twoN * 32;
    float* partial        = (float*)((char*)d_ws + fixed);

    int PS = 128;                        // point split; 2048 blocks, 8/CU
    while (PS > 1 && fixed + (size_t)PS * QT * sizeof(float) > ws_size) PS >>= 1;

    prep_kernel<<<(twoN + 255) / 256, 256, 0, stream>>>(src, tgt, P4, pairBuf,
                                                        acc, counter, twoN);

    const int blocks = 4 * (N / (TPB * Q)) * PS;
    nn_kernel<<<blocks, TPB, 0, stream>>>(P4, pairBuf, partial, N, PS);

    reduce_kernel<<<QT / 256, 256, 0, stream>>>(P4, partial, acc, counter, out, N, PS);
}

// Round 6
// 62.128 us; speedup vs baseline: 1.0189x; 1.0189x over previous
//
#include <hip/hip_runtime.h>

// ============================================================================
// PGALoss, analytically reduced:
//   per-point loss = sqrt(1 + d^2) + d,  d = NN distance
//   out = 0.5 * sum_dir clip((mean loss - 1)/2, 0, 1)
// d^2 = min_m(||p||^2 - 2 q.p) + ||q||^2
//
// R6: back to LDS broadcast (R5's VMEM inner loop regressed), but Q=16
// queries/thread so the per-CU LDS pipe (1 ds_read_b128 per point per wave,
// ~12cyc) is no longer oversubscribed vs VALU (8 packed instrs per point-pair
// per query-pair... net 2.0 lane-instr/pair-eval).  Points packed in pairs
// {x0,x1,y0,y1}/{z0,z1,w0,w1} -> v_pk_fma_f32 + v_min3_f32.
// No prep kernel, no memsets (acc/counter zeroed by nn block 0), 2 kernels.
// ============================================================================

typedef float v2f __attribute__((ext_vector_type(2)));

#define TPB 256
#define Q   16    // queries per thread; QPB = 4096

// ws layout:
//   [0,16)  : double acc[2]
//   [32,36) : uint counter
//   [64,...): float partial[PS][QT]

__global__ __launch_bounds__(TPB)
void nn_kernel(const float* __restrict__ src, const float* __restrict__ tgt,
               float* __restrict__ partial, double* __restrict__ acc,
               unsigned int* __restrict__ counter, int N, int PS) {
    __shared__ float4 tA[512];   // {x0,x1,y0,y1} per point-pair (<=16KB total)
    __shared__ float4 tB[512];   // {z0,z1,w0,w1}

    const int t = threadIdx.x;
    if (blockIdx.x == 0) {
        if (t < 2) acc[t] = 0.0;
        if (t == 2) *counter = 0u;
    }

    const int QPB  = TPB * Q;            // 4096
    const int nqc  = N / QPB;            // 2
    const int bpt  = nqc * PS;
    const int task = blockIdx.x / bpt;   // dir = task>>1, batch = task&1
    const int rem  = blockIdx.x % bpt;
    const int qc   = rem / PS;
    const int pc   = rem % PS;
    const int dir  = task >> 1;
    const int batch= task & 1;
    const int ppb  = N / PS;             // points per block (64 at PS=128)
    const int npairs = ppb / 2;

    const float* qRaw = (dir ? tgt : src) + (size_t)3 * (batch * N + qc * QPB);
    const float* pRaw = (dir ? src : tgt) + (size_t)3 * (batch * N + pc * ppb);

    for (int i = t; i < npairs; i += TPB) {
        const float* pr = pRaw + 6 * i;
        float x0 = pr[0], y0 = pr[1], z0 = pr[2];
        float x1 = pr[3], y1 = pr[4], z1 = pr[5];
        tA[i] = make_float4(x0, x1, y0, y1);
        tB[i] = make_float4(z0, z1,
                            x0 * x0 + y0 * y0 + z0 * z0,
                            x1 * x1 + y1 * y1 + z1 * z1);
    }

    v2f qx[Q], qy[Q], qz[Q];
    float best[Q];
    #pragma unroll
    for (int k = 0; k < Q; ++k) {
        const float* qr = qRaw + 3 * (k * TPB + t);
        float x = qr[0], y = qr[1], z = qr[2];
        qx[k] = (v2f){-2.0f * x, -2.0f * x};   // splat -> op_sel broadcast
        qy[k] = (v2f){-2.0f * y, -2.0f * y};
        qz[k] = (v2f){-2.0f * z, -2.0f * z};
        best[k] = 3.4e38f;
    }
    __syncthreads();

    #pragma unroll 2
    for (int j = 0; j < npairs; j += 2) {
        float4 a0 = tA[j],     b0 = tB[j];
        float4 a1 = tA[j + 1], b1 = tB[j + 1];
        v2f px0 = (v2f){a0.x, a0.y}, py0 = (v2f){a0.z, a0.w};
        v2f pz0 = (v2f){b0.x, b0.y}, pw0 = (v2f){b0.z, b0.w};
        v2f px1 = (v2f){a1.x, a1.y}, py1 = (v2f){a1.z, a1.w};
        v2f pz1 = (v2f){b1.x, b1.y}, pw1 = (v2f){b1.z, b1.w};
        #pragma unroll
        for (int k = 0; k < Q; ++k) {
            v2f d0 = __builtin_elementwise_fma(px0, qx[k],
                     __builtin_elementwise_fma(py0, qy[k],
                     __builtin_elementwise_fma(pz0, qz[k], pw0)));
            v2f d1 = __builtin_elementwise_fma(px1, qx[k],
                     __builtin_elementwise_fma(py1, qy[k],
                     __builtin_elementwise_fma(pz1, qz[k], pw1)));
            best[k] = fminf(fminf(d0.x, d0.y), best[k]);   // v_min3_f32
            best[k] = fminf(fminf(d1.x, d1.y), best[k]);
        }
    }

    // store WITHOUT +qq (reduce adds it); deterministic plain stores
    float* dst = partial + (size_t)pc * (4 * N) + (size_t)task * N + qc * QPB + t;
    #pragma unroll
    for (int k = 0; k < Q; ++k) dst[k * TPB] = best[k];
}

__global__ __launch_bounds__(256)
void reduce_kernel(const float* __restrict__ src, const float* __restrict__ tgt,
                   const float* __restrict__ partial, double* __restrict__ acc,
                   unsigned int* __restrict__ counter, float* __restrict__ out,
                   int N, int PS) {
    const int gq = blockIdx.x * 256 + threadIdx.x;   // [0, 4N)
    const int QT = 4 * N;
    float best = 3.4e38f;
    #pragma unroll 8
    for (int ps = 0; ps < PS; ++ps)
        best = fminf(best, partial[(size_t)ps * QT + gq]);

    const int dir = gq / (2 * N);                    // wave-uniform
    const int ci  = gq & (2 * N - 1);
    const float* qr = (dir ? tgt : src) + (size_t)3 * ci;
    float qq = qr[0] * qr[0] + qr[1] * qr[1] + qr[2] * qr[2];

    float d2 = fmaxf(best + qq, 0.0f);
    float f  = sqrtf(1.0f + d2) + sqrtf(d2);
    for (int o = 32; o > 0; o >>= 1) f += __shfl_down(f, o);
    if ((threadIdx.x & 63) == 0) atomicAdd(&acc[dir], (double)f);
    __syncthreads();
    if (threadIdx.x == 0) {
        __threadfence();
        unsigned int old = atomicAdd(counter, 1u);
        if (old == gridDim.x - 1) {                  // last block finalizes
            double s0 = atomicAdd(&acc[0], 0.0);
            double s1 = atomicAdd(&acc[1], 0.0);
            double inv = 1.0 / (double)(2 * N);
            double l0 = (s0 * inv - 1.0) * 0.5;
            double l1 = (s1 * inv - 1.0) * 0.5;
            l0 = l0 < 0.0 ? 0.0 : (l0 > 1.0 ? 1.0 : l0);
            l1 = l1 < 0.0 ? 0.0 : (l1 > 1.0 ? 1.0 : l1);
            out[0] = (float)(0.5 * (l0 + l1));
        }
    }
}

extern "C" void kernel_launch(void* const* d_in, const int* in_sizes, int n_in,
                              void* d_out, int out_size, void* d_ws, size_t ws_size,
                              hipStream_t stream) {
    const float* src = (const float*)d_in[0];
    const float* tgt = (const float*)d_in[1];
    float* out = (float*)d_out;

    const int twoN = in_sizes[0] / 3;    // 16384
    const int N    = twoN / 2;           // 8192
    const int QT   = 4 * N;              // 32768

    double* acc           = (double*)d_ws;
    unsigned int* counter = (unsigned int*)((char*)d_ws + 32);
    float* partial        = (float*)((char*)d_ws + 64);

    int PS = 128;                        // 1024 blocks -> 4 blocks/CU
    while (PS > 8 && 64 + (size_t)PS * QT * sizeof(float) > ws_size) PS >>= 1;
    while (PS > 8 && (N / PS) % 4 != 0) PS >>= 1;

    const int blocks = 4 * (N / (TPB * Q)) * PS;
    nn_kernel<<<blocks, TPB, 0, stream>>>(src, tgt, partial, acc, counter, N, PS);

    reduce_kernel<<<QT / 256, 256, 0, stream>>>(src, tgt, partial, acc, counter,
                                                out, N, PS);
}

// Round 7
// 49.735 us; speedup vs baseline: 1.2728x; 1.2492x over previous
//
#include <hip/hip_runtime.h>

// ============================================================================
// PGALoss, analytically reduced:
//   per-point loss = sqrt(1 + d^2) + d,  d = NN distance
//   out = 0.5 * sum_dir clip((mean loss - 1)/2, 0, 1)
// d^2 = min_m(||p||^2 - 2 q.p) + ||q||^2
//
// R7: R4 structure (proven), Q=8 (halves LDS-pipe traffic, the measured
// bottleneck: broadcast ds_read_b128 ~12cyc on the one LDS pipe/CU),
// PS=64 keeps ppb=128 so per-block query-load overhead stays amortized
// (R6's mistake). Packed point-pairs {x0,x1,y0,y1}/{z0,z1,w0,w1} ->
// v_pk_fma_f32 + v_min3_f32. Deterministic partial stores, 2 kernels,
// no memsets (acc/counter zeroed by nn block 0).
// ============================================================================

typedef float v2f __attribute__((ext_vector_type(2)));

#define TPB 256
#define Q   8     // queries per thread; QPB = 2048

// ws layout:
//   [0,16)  : double acc[2]
//   [32,36) : uint counter
//   [64,...): float partial[PS][QT]

__global__ __launch_bounds__(TPB)
void nn_kernel(const float* __restrict__ src, const float* __restrict__ tgt,
               float* __restrict__ partial, double* __restrict__ acc,
               unsigned int* __restrict__ counter, int N, int PS) {
    __shared__ float4 tA[256];   // {x0,x1,y0,y1} per point-pair
    __shared__ float4 tB[256];   // {z0,z1,w0,w1}

    const int t = threadIdx.x;
    if (blockIdx.x == 0) {
        if (t < 2) acc[t] = 0.0;
        if (t == 2) *counter = 0u;
    }

    const int QPB  = TPB * Q;            // 2048
    const int nqc  = N / QPB;            // 4
    const int bpt  = nqc * PS;
    const int task = blockIdx.x / bpt;   // dir = task>>1, batch = task&1
    const int rem  = blockIdx.x % bpt;
    const int qc   = rem / PS;
    const int pc   = rem % PS;
    const int dir  = task >> 1;
    const int batch= task & 1;
    const int ppb  = N / PS;             // points per block (128 at PS=64)
    const int npairs = ppb / 2;          // 64

    const float* qRaw = (dir ? tgt : src) + (size_t)3 * (batch * N + qc * QPB);
    const float* pRaw = (dir ? src : tgt) + (size_t)3 * (batch * N + pc * ppb);

    // stage point pairs (64 pairs -> first 64 threads)
    for (int i = t; i < npairs; i += TPB) {
        const float* pr = pRaw + 6 * i;
        float x0 = pr[0], y0 = pr[1], z0 = pr[2];
        float x1 = pr[3], y1 = pr[4], z1 = pr[5];
        tA[i] = make_float4(x0, x1, y0, y1);
        tB[i] = make_float4(z0, z1,
                            x0 * x0 + y0 * y0 + z0 * z0,
                            x1 * x1 + y1 * y1 + z1 * z1);
    }

    v2f qx[Q], qy[Q], qz[Q];
    float best0[Q], best1[Q];
    #pragma unroll
    for (int k = 0; k < Q; ++k) {
        const float* qr = qRaw + 3 * (k * TPB + t);
        float x = qr[0], y = qr[1], z = qr[2];
        qx[k] = (v2f){-2.0f * x, -2.0f * x};
        qy[k] = (v2f){-2.0f * y, -2.0f * y};
        qz[k] = (v2f){-2.0f * z, -2.0f * z};
        best0[k] = 3.4e38f;
        best1[k] = 3.4e38f;
    }
    __syncthreads();

    #pragma unroll 4
    for (int j = 0; j < npairs; j += 2) {
        float4 a0 = tA[j],     b0 = tB[j];
        float4 a1 = tA[j + 1], b1 = tB[j + 1];
        v2f px0 = (v2f){a0.x, a0.y}, py0 = (v2f){a0.z, a0.w};
        v2f pz0 = (v2f){b0.x, b0.y}, pw0 = (v2f){b0.z, b0.w};
        v2f px1 = (v2f){a1.x, a1.y}, py1 = (v2f){a1.z, a1.w};
        v2f pz1 = (v2f){b1.x, b1.y}, pw1 = (v2f){b1.z, b1.w};
        #pragma unroll
        for (int k = 0; k < Q; ++k) {
            v2f d0 = __builtin_elementwise_fma(px0, qx[k],
                     __builtin_elementwise_fma(py0, qy[k],
                     __builtin_elementwise_fma(pz0, qz[k], pw0)));
            v2f d1 = __builtin_elementwise_fma(px1, qx[k],
                     __builtin_elementwise_fma(py1, qy[k],
                     __builtin_elementwise_fma(pz1, qz[k], pw1)));
            best0[k] = fminf(fminf(d0.x, d1.x), best0[k]);  // v_min3_f32
            best1[k] = fminf(fminf(d0.y, d1.y), best1[k]);
        }
    }

    // store WITHOUT +qq (reduce adds it); deterministic plain stores
    float* dst = partial + (size_t)pc * (4 * N) + (size_t)task * N + qc * QPB + t;
    #pragma unroll
    for (int k = 0; k < Q; ++k) dst[k * TPB] = fminf(best0[k], best1[k]);
}

__global__ __launch_bounds__(256)
void reduce_kernel(const float* __restrict__ src, const float* __restrict__ tgt,
                   const float* __restrict__ partial, double* __restrict__ acc,
                   unsigned int* __restrict__ counter, float* __restrict__ out,
                   int N, int PS) {
    const int gq = blockIdx.x * 256 + threadIdx.x;   // [0, 4N)
    const int QT = 4 * N;
    float best = 3.4e38f;
    #pragma unroll 8
    for (int ps = 0; ps < PS; ++ps)
        best = fminf(best, partial[(size_t)ps * QT + gq]);

    const int dir = gq / (2 * N);                    // wave-uniform
    const int ci  = gq & (2 * N - 1);
    const float* qr = (dir ? tgt : src) + (size_t)3 * ci;
    float qq = qr[0] * qr[0] + qr[1] * qr[1] + qr[2] * qr[2];

    float d2 = fmaxf(best + qq, 0.0f);
    float f  = sqrtf(1.0f + d2) + sqrtf(d2);
    for (int o = 32; o > 0; o >>= 1) f += __shfl_down(f, o);
    if ((threadIdx.x & 63) == 0) atomicAdd(&acc[dir], (double)f);
    __syncthreads();
    if (threadIdx.x == 0) {
        __threadfence();
        unsigned int old = atomicAdd(counter, 1u);
        if (old == gridDim.x - 1) {                  // last block finalizes
            double s0 = atomicAdd(&acc[0], 0.0);
            double s1 = atomicAdd(&acc[1], 0.0);
            double inv = 1.0 / (double)(2 * N);
            double l0 = (s0 * inv - 1.0) * 0.5;
            double l1 = (s1 * inv - 1.0) * 0.5;
            l0 = l0 < 0.0 ? 0.0 : (l0 > 1.0 ? 1.0 : l0);
            l1 = l1 < 0.0 ? 0.0 : (l1 > 1.0 ? 1.0 : l1);
            out[0] = (float)(0.5 * (l0 + l1));
        }
    }
}

extern "C" void kernel_launch(void* const* d_in, const int* in_sizes, int n_in,
                              void* d_out, int out_size, void* d_ws, size_t ws_size,
                              hipStream_t stream) {
    const float* src = (const float*)d_in[0];
    const float* tgt = (const float*)d_in[1];
    float* out = (float*)d_out;

    const int twoN = in_sizes[0] / 3;    // 16384
    const int N    = twoN / 2;           // 8192
    const int QT   = 4 * N;              // 32768

    double* acc           = (double*)d_ws;
    unsigned int* counter = (unsigned int*)((char*)d_ws + 32);
    float* partial        = (float*)((char*)d_ws + 64);

    int PS = 64;                         // ppb=128: big enough inner loop (R6 lesson)
    while (PS > 16 && 64 + (size_t)PS * QT * sizeof(float) > ws_size) PS >>= 1;

    const int blocks = 4 * (N / (TPB * Q)) * PS;   // 1024 at PS=64
    nn_kernel<<<blocks, TPB, 0, stream>>>(src, tgt, partial, acc, counter, N, PS);

    reduce_kernel<<<QT / 256, 256, 0, stream>>>(src, tgt, partial, acc, counter,
                                                out, N, PS);
}